// Round 5
// baseline (1833.983 us; speedup 1.0000x reference)
//
#include <hip/hip_runtime.h>

// ---------------- problem constants ----------------
#define N_WORDS 16384
#define MAXL    16
#define VOCABSZ 128
#define EMBD    64
#define HID     256
#define GATES   1024        // 4*HID
#define KTOT    320         // HID + EMBD (x folded into K)
#define AROW    328         // A row stride in shorts (656 B = 640 + 16 pad)
#define M_TILE  64          // words per workgroup
#define NT      256         // word tiles (N_WORDS / M_TILE)

typedef __attribute__((ext_vector_type(8))) short bf16x8;  // 8 bf16 = 4 VGPRs
typedef __attribute__((ext_vector_type(4))) float f32x4;
typedef __attribute__((ext_vector_type(4))) int   i32x4;

// ---------------- workspace layout (bytes) ----------------
// wsw : swizzled weights, B-fragment order: [dir][Tg 0..63][kk 0..9][lane 0..63][8 bf16]
#define OFF_WSW   0ul          // 2*64*10*64*16 = 1310720
#define OFF_EMB   1310720ul    // 128*64 bf16 = 16384
#define OFF_BIAS  1327104ul    // 2*1024 f32 = 8192 (interleaved unit-major)
#define OFF_SORT  1335296ul    // 16384 ints = 65536
#define OFF_HIST  1400832ul    // 16 ints
#define OFF_BASE  1400896ul    // 16 ints
#define OFF_CNT   1400960ul    // 16 ints

__device__ inline short tobf(float f) {           // fp32 -> bf16 RNE
  unsigned u = __float_as_uint(f);
  unsigned r = (u + 0x7fffu + ((u >> 16) & 1u)) >> 16;
  return (short)r;
}
// R1-proven quad exchanges via ds_swizzle (BitMode: xor-1 / xor-2 within quad)
__device__ inline float swz1(float x) {
  return __int_as_float(__builtin_amdgcn_ds_swizzle(__float_as_int(x), 0x041F));
}
__device__ inline float swz2(float x) {
  return __int_as_float(__builtin_amdgcn_ds_swizzle(__float_as_int(x), 0x081F));
}
// R1-proven activations (libm exp2f + division)
__device__ inline float fsig(float x) { return 1.0f / (1.0f + exp2f(x * -1.4426950408889634f)); }
__device__ inline float ftanhf(float x) { return 1.0f - 2.0f / (1.0f + exp2f(x * 2.8853900817779268f)); }

// ---------------- prep: weight swizzle into B-fragment layout ----------------
// n (interleaved gate col) = 4*unit + type ; original gate row g = type*256 + unit
__global__ void prep_w(const float* __restrict__ Wihf, const float* __restrict__ Whhf,
                       const float* __restrict__ Wihb, const float* __restrict__ Whhb,
                       short* __restrict__ wsw) {
  int id = blockIdx.x * 256 + threadIdx.x;       // 2*64*10*64 = 81920
  if (id >= 81920) return;
  int d    = id / 40960;
  int r    = id % 40960;
  int Tg   = r / 640;
  int r2   = r % 640;
  int kk   = r2 / 64;
  int lane = r2 % 64;
  int n  = Tg * 16 + (lane & 15);
  int u  = n >> 2, ty = n & 3;
  int g  = ty * 256 + u;
  int kb = kk * 32 + (lane >> 4) * 8;
  const float* Wih = d ? Wihb : Wihf;
  const float* Whh = d ? Whhb : Whhf;
  bf16x8 v;
#pragma unroll
  for (int j = 0; j < 8; ++j) {
    int k = kb + j;
    float f = (k < HID) ? Whh[g * HID + k] : Wih[g * EMBD + (k - HID)];
    v[j] = tobf(f);
  }
  ((bf16x8*)wsw)[id] = v;
}

// emb -> bf16, biases -> interleaved sum
__global__ void prep_misc(const float* __restrict__ emb,
                          const float* __restrict__ bihf, const float* __restrict__ bhhf,
                          const float* __restrict__ bihb, const float* __restrict__ bhhb,
                          short* __restrict__ embw, float* __restrict__ biasg) {
  int id = blockIdx.x * 256 + threadIdx.x;       // 8192 + 2048 = 10240
  if (id < VOCABSZ * EMBD) {
    embw[id] = tobf(emb[id]);
  } else {
    int r = id - VOCABSZ * EMBD;
    if (r < 2048) {
      int d = r >> 10, n = r & 1023;
      int g = (n & 3) * 256 + (n >> 2);
      biasg[r] = d ? (bihb[g] + bhhb[g]) : (bihf[g] + bhhf[g]);
    }
  }
}

// ---------------- length bucketing ----------------
__global__ void k_hist(const int* __restrict__ lengths, int* __restrict__ hist) {
  int id = blockIdx.x * 256 + threadIdx.x;
  if (id < N_WORDS) atomicAdd(&hist[lengths[id] - 1], 1);
}
__global__ void k_scan(const int* __restrict__ hist, int* __restrict__ basep) {
  if (threadIdx.x == 0 && blockIdx.x == 0) {
    int s = 0;
    for (int i = 0; i < 16; ++i) { basep[i] = s; s += hist[i]; }
  }
}
__global__ void k_scat(const int* __restrict__ lengths, const int* __restrict__ basep,
                       int* __restrict__ cnt, int* __restrict__ sorted) {
  int id = blockIdx.x * 256 + threadIdx.x;
  if (id < N_WORDS) {
    int b = lengths[id] - 1;
    int p = basep[b] + atomicAdd(&cnt[b], 1);
    sorted[p] = id;
  }
}

// ---------------- main fused BiLSTM kernel ----------------
// grid = 512: block pb -> dir = pb&1 ; tile interleaved short/long for balance.
// wave w owns interleaved gate cols [256w, 256w+256) == units [64w, 64w+64), all 4 gate types.
// SINGLE delta vs R1 (passing): cell state c moved from global ws into lane-private
// VGPRs creg[16][4] (step-invariant lane mapping), which requires full unroll of the
// T-tile loop for static indexing. Everything else identical to R1.
__global__ __launch_bounds__(256, 1) void lstm_main(
    const int* __restrict__ char_ids, const int* __restrict__ lengths,
    const short* __restrict__ wsw, const short* __restrict__ embw,
    const float* __restrict__ biasg, const int* __restrict__ sorted,
    float* __restrict__ out) {
  __shared__ __align__(16) short A[M_TILE * AROW];   // [word][ h(256) | x(64) | pad(8) ] bf16
  __shared__ __align__(16) int   charl[M_TILE * 16];
  __shared__ __align__(16) float biasl[GATES];
  __shared__ int lenl[M_TILE];
  __shared__ int swl[M_TILE];

  const int tid  = threadIdx.x;
  const int lane = tid & 63;
  const int wv   = tid >> 6;
  const int pb   = blockIdx.x;
  const int dir  = pb & 1;
  const int qb   = pb >> 1;
  const int tile = (qb & 1) ? (255 - (qb >> 1)) : (qb >> 1);

  if (tid < M_TILE) {
    int sw = sorted[tile * M_TILE + tid];
    swl[tid]  = sw;
    lenl[tid] = lengths[sw];
  }
  ((f32x4*)biasl)[tid] = ((const f32x4*)(biasg + dir * GATES))[tid];
  for (int i = tid; i < M_TILE * AROW / 2; i += 256) ((int*)A)[i] = 0;     // h=0 init
  __syncthreads();

  { // char ids for the tile (via sorted ids)
    int w = tid >> 2, ch = tid & 3;
    ((i32x4*)charl)[tid] = ((const i32x4*)(char_ids + swl[w] * 16))[ch];
  }
  int Lmax = lenl[lane];
  for (int o = 32; o; o >>= 1) { int v = __shfl_xor(Lmax, o, 64); Lmax = Lmax > v ? Lmax : v; }
  __syncthreads();  // charl ready

  // stage x for timestep tt into A cols [256,320): wave w covers words 16w..16w+15, 4 lanes/word
  auto gather_x = [&](int tt) {
    int wl = wv * 16 + (lane >> 2);
    int part = lane & 3;
    int lw = lenl[wl];
    int pos = (dir == 0) ? tt : (lw - 1 - tt);
    pos = pos < 0 ? 0 : (pos > 15 ? 15 : pos);
    int cid = charl[wl * 16 + pos];
    const bf16x8* src = (const bf16x8*)(embw + cid * EMBD + part * 16);
    bf16x8 e0 = src[0], e1 = src[1];
    *(bf16x8*)(A + wl * AROW + HID + part * 16)     = e0;
    *(bf16x8*)(A + wl * AROW + HID + part * 16 + 8) = e1;
  };
  gather_x(0);

  // step-invariant lane constants: after quad transpose, lane owns
  // word = mt*16 + (lane>>4)*4 + (lane&3), unit = 64*wv + T*4 + ((lane>>2)&3)
  const int q4   = (lane >> 2) & 3;
  const int colc = lane & 15;
  int lenv[4], hadr[4], ooff[4];
#pragma unroll
  for (int mt = 0; mt < 4; ++mt) {
    int wl = mt * 16 + ((lane >> 4) << 2) + (lane & 3);
    lenv[mt]  = lenl[wl];
    hadr[mt]  = wl * AROW + wv * 64 + q4;                  // bf16 h slot in A
    ooff[mt]  = swl[wl] * 512 + dir * 256 + wv * 64 + q4;  // fp32 out slot
  }
  const short* wp = wsw + ((size_t)dir * 64 + wv * 16) * 10 * 64 * 8 + lane * 8;

  // cell state in registers: creg[T][mt] = c(word(mt,lane), unit 64wv+4T+q4)
  float creg[16][4];
#pragma unroll
  for (int T = 0; T < 16; ++T)
#pragma unroll
    for (int mt = 0; mt < 4; ++mt) creg[T][mt] = 0.0f;

  __syncthreads();  // x / zeros visible

#pragma unroll 1
  for (int t = 0; t < Lmax; ++t) {
    bf16x8 bA[10], bB[10];
#pragma unroll
    for (int kk = 0; kk < 10; ++kk) bA[kk] = *(const bf16x8*)(wp + kk * 512);

    bf16x8 a[4][10];  // A fragments: lane = A[m=mt*16+(l&15)][k = kk*32 + (l>>4)*8 + j]
#pragma unroll
    for (int mt = 0; mt < 4; ++mt)
#pragma unroll
      for (int kk = 0; kk < 10; ++kk)
        a[mt][kk] = *(const bf16x8*)(A + (mt * 16 + colc) * AROW + kk * 32 + (lane >> 4) * 8);

    __syncthreads();  // all waves snapshotted A -> safe to overwrite h/x below

    auto do_tile = [&](int T, bf16x8(&bc)[10], bf16x8(&bn)[10], int Tpre) {
      if (Tpre >= 0) {  // prefetch next tile's B frags (keeps vmcnt > 0 across MFMAs)
#pragma unroll
        for (int kk = 0; kk < 10; ++kk) bn[kk] = *(const bf16x8*)(wp + (Tpre * 10 + kk) * 512);
      }
      float bl = biasl[wv * 256 + T * 16 + colc];
      f32x4 acc[4];
#pragma unroll
      for (int mt = 0; mt < 4; ++mt) acc[mt] = (f32x4){bl, bl, bl, bl};
#pragma unroll
      for (int kk = 0; kk < 10; ++kk)
#pragma unroll
        for (int mt = 0; mt < 4; ++mt)  // 4 independent acc chains -> MFMA ILP
          acc[mt] = __builtin_amdgcn_mfma_f32_16x16x32_bf16(a[mt][kk], bc[kk], acc[mt], 0, 0, 0);

      bool lo1 = (lane & 1) == 0;
      bool lo2 = (lane & 2) == 0;
#pragma unroll
      for (int mt = 0; mt < 4; ++mt) {
        // 4x4 transpose across each aligned lane-quad: regs(word) x lanes(gate-type) -> regs(type)
        float v0 = acc[mt][0], v1 = acc[mt][1], v2 = acc[mt][2], v3 = acc[mt][3];
        float r0 = swz1(v0), r1 = swz1(v1);
        float u0 = lo1 ? v0 : r1;
        float u1 = lo1 ? r0 : v1;
        float r2 = swz1(v2), r3 = swz1(v3);
        float u2 = lo1 ? v2 : r3;
        float u3 = lo1 ? r2 : v3;
        float s0 = swz2(u0), s2 = swz2(u2);
        float w0 = lo2 ? u0 : s2;
        float w2 = lo2 ? s0 : u2;
        float s1 = swz2(u1), s3 = swz2(u3);
        float w1 = lo2 ? u1 : s3;
        float w3 = lo2 ? s1 : u3;
        // w0..w3 = i,f,g,o pre-activations (fp32)
        float ig = fsig(w0), fg = fsig(w1);
        float gg = ftanhf(w2), og = fsig(w3);
        float co_v = creg[T][mt];
        float c2 = fg * co_v + ig * gg;
        float h2 = og * ftanhf(c2);
        bool act = t < lenv[mt];
        creg[T][mt] = act ? c2 : co_v;
        if (act) A[hadr[mt] + T * 4] = tobf(h2);            // freeze h when masked
        if (t == lenv[mt] - 1) out[ooff[mt] + T * 4] = h2;  // final h in fp32
      }
    };

#pragma unroll
    for (int T2 = 0; T2 < 16; T2 += 2) {   // FULL unroll: creg indices must be static
      do_tile(T2,     bA, bB, T2 + 1);
      do_tile(T2 + 1, bB, bA, (T2 + 2 < 16) ? (T2 + 2) : -1);
    }

    gather_x(t + 1);   // x for next step (clamped; dead steps are masked)
    __syncthreads();   // h/x writes visible before next step's A reads
  }
}

// ---------------- launch ----------------
extern "C" void kernel_launch(void* const* d_in, const int* in_sizes, int n_in,
                              void* d_out, int out_size, void* d_ws, size_t ws_size,
                              hipStream_t stream) {
  const int*   char_ids = (const int*)d_in[0];
  const int*   lengths  = (const int*)d_in[1];
  const float* emb      = (const float*)d_in[2];
  const float* Wihf     = (const float*)d_in[3];
  const float* Whhf     = (const float*)d_in[4];
  const float* bihf     = (const float*)d_in[5];
  const float* bhhf     = (const float*)d_in[6];
  const float* Wihb     = (const float*)d_in[7];
  const float* Whhb     = (const float*)d_in[8];
  const float* bihb     = (const float*)d_in[9];
  const float* bhhb     = (const float*)d_in[10];

  char* ws = (char*)d_ws;
  short* wsw   = (short*)(ws + OFF_WSW);
  short* embw  = (short*)(ws + OFF_EMB);
  float* biasg = (float*)(ws + OFF_BIAS);
  int*   sortd = (int*)(ws + OFF_SORT);
  int*   hist  = (int*)(ws + OFF_HIST);
  int*   basep = (int*)(ws + OFF_BASE);
  int*   cnt   = (int*)(ws + OFF_CNT);

  hipMemsetAsync(hist, 0, 192, stream);  // hist + base + cnt
  k_hist<<<64, 256, 0, stream>>>(lengths, hist);
  k_scan<<<1, 64, 0, stream>>>(hist, basep);
  k_scat<<<64, 256, 0, stream>>>(lengths, basep, cnt, sortd);
  prep_w<<<320, 256, 0, stream>>>(Wihf, Whhf, Wihb, Whhb, wsw);
  prep_misc<<<40, 256, 0, stream>>>(emb, bihf, bhhf, bihb, bhhb, embw, biasg);
  lstm_main<<<512, 256, 0, stream>>>(char_ids, lengths, wsw, embw, biasg, sortd,
                                     (float*)d_out);
}

// Round 6
// 929.016 us; speedup vs baseline: 1.9741x; 1.9741x over previous
//
#include <hip/hip_runtime.h>

// ---------------- problem constants ----------------
#define N_WORDS 16384
#define MAXL    16
#define VOCABSZ 128
#define EMBD    64
#define HID     256
#define GATES   1024        // 4*HID
#define KTOT    320         // HID + EMBD (x folded into K)
#define AROW    328         // A row stride in shorts (656 B = 640 + 16 pad)
#define M_TILE  64          // words per workgroup
#define NT      256         // word tiles (N_WORDS / M_TILE)

typedef __attribute__((ext_vector_type(8))) short bf16x8;  // 8 bf16 = 4 VGPRs
typedef __attribute__((ext_vector_type(4))) float f32x4;
typedef __attribute__((ext_vector_type(4))) int   i32x4;

// ---------------- workspace layout (bytes) ----------------
// wsw : swizzled weights, B-fragment order: [dir][Tg 0..63][kk 0..9][lane 0..63][8 bf16]
#define OFF_WSW   0ul          // 2*64*10*64*16 = 1310720
#define OFF_EMB   1310720ul    // 128*64 bf16 = 16384
#define OFF_BIAS  1327104ul    // 2*1024 f32 = 8192 (interleaved unit-major)
#define OFF_SORT  1335296ul    // 16384 ints = 65536
#define OFF_HIST  1400832ul    // 16 ints
#define OFF_BASE  1400896ul    // 16 ints
#define OFF_CNT   1400960ul    // 16 ints
#define OFF_C     1401088ul    // 512 blocks * 16T * 4wv * 64 lanes * 16B = 33554432
                               // COALESCED fp32x4 cell state (lane-contiguous per (T,wv))

__device__ inline short tobf(float f) {           // fp32 -> bf16 RNE
  unsigned u = __float_as_uint(f);
  unsigned r = (u + 0x7fffu + ((u >> 16) & 1u)) >> 16;
  return (short)r;
}
// R1-proven quad exchanges via ds_swizzle (BitMode: xor-1 / xor-2 within quad)
__device__ inline float swz1(float x) {
  return __int_as_float(__builtin_amdgcn_ds_swizzle(__float_as_int(x), 0x041F));
}
__device__ inline float swz2(float x) {
  return __int_as_float(__builtin_amdgcn_ds_swizzle(__float_as_int(x), 0x081F));
}
// R1-proven activations (libm exp2f + division)
__device__ inline float fsig(float x) { return 1.0f / (1.0f + exp2f(x * -1.4426950408889634f)); }
__device__ inline float ftanhf(float x) { return 1.0f - 2.0f / (1.0f + exp2f(x * 2.8853900817779268f)); }

// ---------------- prep: weight swizzle into B-fragment layout ----------------
// n (interleaved gate col) = 4*unit + type ; original gate row g = type*256 + unit
__global__ void prep_w(const float* __restrict__ Wihf, const float* __restrict__ Whhf,
                       const float* __restrict__ Wihb, const float* __restrict__ Whhb,
                       short* __restrict__ wsw) {
  int id = blockIdx.x * 256 + threadIdx.x;       // 2*64*10*64 = 81920
  if (id >= 81920) return;
  int d    = id / 40960;
  int r    = id % 40960;
  int Tg   = r / 640;
  int r2   = r % 640;
  int kk   = r2 / 64;
  int lane = r2 % 64;
  int n  = Tg * 16 + (lane & 15);
  int u  = n >> 2, ty = n & 3;
  int g  = ty * 256 + u;
  int kb = kk * 32 + (lane >> 4) * 8;
  const float* Wih = d ? Wihb : Wihf;
  const float* Whh = d ? Whhb : Whhf;
  bf16x8 v;
#pragma unroll
  for (int j = 0; j < 8; ++j) {
    int k = kb + j;
    float f = (k < HID) ? Whh[g * HID + k] : Wih[g * EMBD + (k - HID)];
    v[j] = tobf(f);
  }
  ((bf16x8*)wsw)[id] = v;
}

// emb -> bf16, biases -> interleaved sum
__global__ void prep_misc(const float* __restrict__ emb,
                          const float* __restrict__ bihf, const float* __restrict__ bhhf,
                          const float* __restrict__ bihb, const float* __restrict__ bhhb,
                          short* __restrict__ embw, float* __restrict__ biasg) {
  int id = blockIdx.x * 256 + threadIdx.x;       // 8192 + 2048 = 10240
  if (id < VOCABSZ * EMBD) {
    embw[id] = tobf(emb[id]);
  } else {
    int r = id - VOCABSZ * EMBD;
    if (r < 2048) {
      int d = r >> 10, n = r & 1023;
      int g = (n & 3) * 256 + (n >> 2);
      biasg[r] = d ? (bihb[g] + bhhb[g]) : (bihf[g] + bhhf[g]);
    }
  }
}

// ---------------- length bucketing ----------------
__global__ void k_hist(const int* __restrict__ lengths, int* __restrict__ hist) {
  int id = blockIdx.x * 256 + threadIdx.x;
  if (id < N_WORDS) atomicAdd(&hist[lengths[id] - 1], 1);
}
__global__ void k_scan(const int* __restrict__ hist, int* __restrict__ basep) {
  if (threadIdx.x == 0 && blockIdx.x == 0) {
    int s = 0;
    for (int i = 0; i < 16; ++i) { basep[i] = s; s += hist[i]; }
  }
}
__global__ void k_scat(const int* __restrict__ lengths, const int* __restrict__ basep,
                       int* __restrict__ cnt, int* __restrict__ sorted) {
  int id = blockIdx.x * 256 + threadIdx.x;
  if (id < N_WORDS) {
    int b = lengths[id] - 1;
    int p = basep[b] + atomicAdd(&cnt[b], 1);
    sorted[p] = id;
  }
}

// ---------------- main fused BiLSTM kernel ----------------
// grid = 512: block pb -> dir = pb&1 ; tile interleaved short/long for balance.
// wave w owns interleaved gate cols [256w, 256w+256) == units [64w, 64w+64), all 4 gate types.
// SINGLE delta vs R1 (passing, 873 us): cell state stays in global ws but in a
// COALESCED layout — one f32x4 per lane, lane-contiguous per (T, wave):
//   cws4[((pb*16 + T)*4 + wv)*64 + lane]  (components = 4 mt words)
// R1's c traffic was 4 B/lane at 1 KB stride -> ~4x line amplification, 1.25 GB HBM
// writes at 1.6 TB/s = the whole kernel. Same data, coalesced: 1 KB/wave-access.
__global__ __launch_bounds__(256, 1) void lstm_main(
    const int* __restrict__ char_ids, const int* __restrict__ lengths,
    const short* __restrict__ wsw, const short* __restrict__ embw,
    const float* __restrict__ biasg, const int* __restrict__ sorted,
    f32x4* __restrict__ cws4, float* __restrict__ out) {
  __shared__ __align__(16) short A[M_TILE * AROW];   // [word][ h(256) | x(64) | pad(8) ] bf16
  __shared__ __align__(16) int   charl[M_TILE * 16];
  __shared__ __align__(16) float biasl[GATES];
  __shared__ int lenl[M_TILE];
  __shared__ int swl[M_TILE];

  const int tid  = threadIdx.x;
  const int lane = tid & 63;
  const int wv   = tid >> 6;
  const int pb   = blockIdx.x;
  const int dir  = pb & 1;
  const int qb   = pb >> 1;
  const int tile = (qb & 1) ? (255 - (qb >> 1)) : (qb >> 1);

  // this block's c slice: [T 0..15][wv 0..3][lane 0..63] f32x4
  f32x4* cb = cws4 + (size_t)pb * (16 * 4 * 64);

  if (tid < M_TILE) {
    int sw = sorted[tile * M_TILE + tid];
    swl[tid]  = sw;
    lenl[tid] = lengths[sw];
  }
  ((f32x4*)biasl)[tid] = ((const f32x4*)(biasg + dir * GATES))[tid];
  for (int i = tid; i < M_TILE * AROW / 2; i += 256) ((int*)A)[i] = 0;     // h=0 init
  for (int i = tid; i < 16 * 4 * 64; i += 256) cb[i] = (f32x4){0.f, 0.f, 0.f, 0.f};  // c=0
  __syncthreads();

  { // char ids for the tile (via sorted ids)
    int w = tid >> 2, ch = tid & 3;
    ((i32x4*)charl)[tid] = ((const i32x4*)(char_ids + swl[w] * 16))[ch];
  }
  int Lmax = lenl[lane];
  for (int o = 32; o; o >>= 1) { int v = __shfl_xor(Lmax, o, 64); Lmax = Lmax > v ? Lmax : v; }
  __syncthreads();  // charl ready

  // stage x for timestep tt into A cols [256,320): wave w covers words 16w..16w+15, 4 lanes/word
  auto gather_x = [&](int tt) {
    int wl = wv * 16 + (lane >> 2);
    int part = lane & 3;
    int lw = lenl[wl];
    int pos = (dir == 0) ? tt : (lw - 1 - tt);
    pos = pos < 0 ? 0 : (pos > 15 ? 15 : pos);
    int cid = charl[wl * 16 + pos];
    const bf16x8* src = (const bf16x8*)(embw + cid * EMBD + part * 16);
    bf16x8 e0 = src[0], e1 = src[1];
    *(bf16x8*)(A + wl * AROW + HID + part * 16)     = e0;
    *(bf16x8*)(A + wl * AROW + HID + part * 16 + 8) = e1;
  };
  gather_x(0);

  // step-invariant lane constants: after quad transpose, lane owns
  // word = mt*16 + (lane>>4)*4 + (lane&3), unit = 64*wv + T*4 + ((lane>>2)&3)
  const int q4   = (lane >> 2) & 3;
  const int colc = lane & 15;
  int lenv[4], hadr[4], ooff[4];
#pragma unroll
  for (int mt = 0; mt < 4; ++mt) {
    int wl = mt * 16 + ((lane >> 4) << 2) + (lane & 3);
    lenv[mt]  = lenl[wl];
    hadr[mt]  = wl * AROW + wv * 64 + q4;                  // bf16 h slot in A
    ooff[mt]  = swl[wl] * 512 + dir * 256 + wv * 64 + q4;  // fp32 out slot
  }
  const short* wp = wsw + ((size_t)dir * 64 + wv * 16) * 10 * 64 * 8 + lane * 8;
  f32x4* cwl = cb + wv * 64 + lane;   // + T*256 per tile

  __syncthreads();  // x / zeros visible

#pragma unroll 1
  for (int t = 0; t < Lmax; ++t) {
    bf16x8 bA[10], bB[10];
#pragma unroll
    for (int kk = 0; kk < 10; ++kk) bA[kk] = *(const bf16x8*)(wp + kk * 512);

    bf16x8 a[4][10];  // A fragments: lane = A[m=mt*16+(l&15)][k = kk*32 + (l>>4)*8 + j]
#pragma unroll
    for (int mt = 0; mt < 4; ++mt)
#pragma unroll
      for (int kk = 0; kk < 10; ++kk)
        a[mt][kk] = *(const bf16x8*)(A + (mt * 16 + colc) * AROW + kk * 32 + (lane >> 4) * 8);

    __syncthreads();  // all waves snapshotted A -> safe to overwrite h/x below

    auto do_tile = [&](int T, bf16x8(&bc)[10], bf16x8(&bn)[10], int Tpre) {
      if (Tpre >= 0) {  // prefetch next tile's B frags (keeps vmcnt > 0 across MFMAs)
#pragma unroll
        for (int kk = 0; kk < 10; ++kk) bn[kk] = *(const bf16x8*)(wp + (Tpre * 10 + kk) * 512);
      }
      f32x4* cp = cwl + T * 256;
      f32x4 co4 = *cp;              // coalesced 1 KB wave load; latency hides under MFMAs
      float bl = biasl[wv * 256 + T * 16 + colc];
      f32x4 acc[4];
#pragma unroll
      for (int mt = 0; mt < 4; ++mt) acc[mt] = (f32x4){bl, bl, bl, bl};
#pragma unroll
      for (int kk = 0; kk < 10; ++kk)
#pragma unroll
        for (int mt = 0; mt < 4; ++mt)  // 4 independent acc chains -> MFMA ILP
          acc[mt] = __builtin_amdgcn_mfma_f32_16x16x32_bf16(a[mt][kk], bc[kk], acc[mt], 0, 0, 0);

      bool lo1 = (lane & 1) == 0;
      bool lo2 = (lane & 2) == 0;
      f32x4 cn4;
#pragma unroll
      for (int mt = 0; mt < 4; ++mt) {
        // 4x4 transpose across each aligned lane-quad: regs(word) x lanes(gate-type) -> regs(type)
        float v0 = acc[mt][0], v1 = acc[mt][1], v2 = acc[mt][2], v3 = acc[mt][3];
        float r0 = swz1(v0), r1 = swz1(v1);
        float u0 = lo1 ? v0 : r1;
        float u1 = lo1 ? r0 : v1;
        float r2 = swz1(v2), r3 = swz1(v3);
        float u2 = lo1 ? v2 : r3;
        float u3 = lo1 ? r2 : v3;
        float s0 = swz2(u0), s2 = swz2(u2);
        float w0 = lo2 ? u0 : s2;
        float w2 = lo2 ? s0 : u2;
        float s1 = swz2(u1), s3 = swz2(u3);
        float w1 = lo2 ? u1 : s3;
        float w3 = lo2 ? s1 : u3;
        // w0..w3 = i,f,g,o pre-activations (fp32)
        float ig = fsig(w0), fg = fsig(w1);
        float gg = ftanhf(w2), og = fsig(w3);
        float co_v = co4[mt];
        float c2 = fg * co_v + ig * gg;
        float h2 = og * ftanhf(c2);
        bool act = t < lenv[mt];
        cn4[mt] = act ? c2 : co_v;
        if (act) A[hadr[mt] + T * 4] = tobf(h2);            // freeze h when masked
        if (t == lenv[mt] - 1) out[ooff[mt] + T * 4] = h2;  // final h in fp32
      }
      *cp = cn4;                    // coalesced 1 KB wave store
    };

#pragma unroll 1
    for (int T2 = 0; T2 < 16; T2 += 2) {   // ping-pong B buffers with static indices
      do_tile(T2,     bA, bB, T2 + 1);
      do_tile(T2 + 1, bB, bA, (T2 + 2 < 16) ? (T2 + 2) : -1);
    }

    gather_x(t + 1);   // x for next step (clamped; dead steps are masked)
    __syncthreads();   // h/x writes visible before next step's A reads
  }
}

// ---------------- launch ----------------
extern "C" void kernel_launch(void* const* d_in, const int* in_sizes, int n_in,
                              void* d_out, int out_size, void* d_ws, size_t ws_size,
                              hipStream_t stream) {
  const int*   char_ids = (const int*)d_in[0];
  const int*   lengths  = (const int*)d_in[1];
  const float* emb      = (const float*)d_in[2];
  const float* Wihf     = (const float*)d_in[3];
  const float* Whhf     = (const float*)d_in[4];
  const float* bihf     = (const float*)d_in[5];
  const float* bhhf     = (const float*)d_in[6];
  const float* Wihb     = (const float*)d_in[7];
  const float* Whhb     = (const float*)d_in[8];
  const float* bihb     = (const float*)d_in[9];
  const float* bhhb     = (const float*)d_in[10];

  char* ws = (char*)d_ws;
  short* wsw   = (short*)(ws + OFF_WSW);
  short* embw  = (short*)(ws + OFF_EMB);
  float* biasg = (float*)(ws + OFF_BIAS);
  int*   sortd = (int*)(ws + OFF_SORT);
  int*   hist  = (int*)(ws + OFF_HIST);
  int*   basep = (int*)(ws + OFF_BASE);
  int*   cnt   = (int*)(ws + OFF_CNT);
  f32x4* cws4  = (f32x4*)(ws + OFF_C);

  hipMemsetAsync(hist, 0, 192, stream);  // hist + base + cnt
  k_hist<<<64, 256, 0, stream>>>(lengths, hist);
  k_scan<<<1, 64, 0, stream>>>(hist, basep);
  k_scat<<<64, 256, 0, stream>>>(lengths, basep, cnt, sortd);
  prep_w<<<320, 256, 0, stream>>>(Wihf, Whhf, Wihb, Whhb, wsw);
  prep_misc<<<40, 256, 0, stream>>>(emb, bihf, bhhf, bihb, bhhb, embw, biasg);
  lstm_main<<<512, 256, 0, stream>>>(char_ids, lengths, wsw, embw, biasg, sortd,
                                     cws4, (float*)d_out);
}

// Round 7
// 557.270 us; speedup vs baseline: 3.2910x; 1.6671x over previous
//
#include <hip/hip_runtime.h>

// ---------------- problem constants ----------------
#define N_WORDS 16384
#define MAXL    16
#define VOCABSZ 128
#define EMBD    64
#define HID     256
#define GATES   1024        // 4*HID
#define KTOT    320         // HID + EMBD (x folded into K)
#define AROW    328         // A row stride in shorts (656 B = 640 + 16 pad)
#define M_TILE  64          // words per workgroup
#define NT      256         // word tiles (N_WORDS / M_TILE)

typedef __attribute__((ext_vector_type(8))) short bf16x8;  // 8 bf16 = 4 VGPRs
typedef __attribute__((ext_vector_type(4))) float f32x4;
typedef __attribute__((ext_vector_type(4))) int   i32x4;

// ---------------- workspace layout (bytes) ----------------
// wsw : swizzled weights, A-fragment order: [dir][R 0..63][kk 0..9][lane 0..63][8 bf16]
//       row-tile R covers units 4R..4R+3, rows m = 4*uu + gate_type (unit-major interleave)
#define OFF_WSW   0ul          // 2*64*10*64*16 = 1310720
#define OFF_EMB   1310720ul    // 128*64 bf16 = 16384
#define OFF_BIAS  1327104ul    // 2*1024 f32 = 8192 (interleaved unit-major: [4*unit+type])
#define OFF_SORT  1335296ul    // 16384 ints = 65536
#define OFF_HIST  1400832ul    // 16 ints
#define OFF_BASE  1400896ul    // 16 ints
#define OFF_CNT   1400960ul    // 16 ints
#define OFF_C     1401088ul    // 512 blocks * 4wv * 16rt * 4ct * 64 lanes * 4B = 33554432
                               // fully-coalesced scalar fp32 cell state

__device__ inline short tobf(float f) {           // fp32 -> bf16 RNE
  unsigned u = __float_as_uint(f);
  unsigned r = (u + 0x7fffu + ((u >> 16) & 1u)) >> 16;
  return (short)r;
}
// raw transcendental units via inline asm (assembles per cdna4_isa.md §3; avoids
// precise-div expansion AND builtin-name availability roulette)
__device__ inline float aexp2(float x) { float r; asm("v_exp_f32 %0, %1" : "=v"(r) : "v"(x)); return r; }
__device__ inline float arcp(float x)  { float r; asm("v_rcp_f32 %0, %1" : "=v"(r) : "v"(x)); return r; }
__device__ inline float fsig(float x)   { return arcp(1.0f + aexp2(x * -1.4426950408889634f)); }
__device__ inline float ftanhf(float x) { return 1.0f - 2.0f * arcp(1.0f + aexp2(x * 2.8853900817779268f)); }

// ---------------- prep: weight swizzle into MFMA *A*-fragment layout ----------------
// A[m][k] for 16x16x32: m = lane&15, k = kk*32 + (lane>>4)*8 + j
// row m of row-tile R: unit = 4R + (m>>2), gate type = m&3, gate row g = type*256 + unit
__global__ void prep_w(const float* __restrict__ Wihf, const float* __restrict__ Whhf,
                       const float* __restrict__ Wihb, const float* __restrict__ Whhb,
                       short* __restrict__ wsw) {
  int id = blockIdx.x * 256 + threadIdx.x;       // 2*64*10*64 = 81920
  if (id >= 81920) return;
  int d    = id / 40960;
  int r    = id % 40960;
  int R    = r / 640;
  int r2   = r % 640;
  int kk   = r2 / 64;
  int lane = r2 % 64;
  int m    = lane & 15;
  int unit = R * 4 + (m >> 2);
  int ty   = m & 3;
  int g    = ty * 256 + unit;
  int kb   = kk * 32 + (lane >> 4) * 8;
  const float* Wih = d ? Wihb : Wihf;
  const float* Whh = d ? Whhb : Whhf;
  bf16x8 v;
#pragma unroll
  for (int j = 0; j < 8; ++j) {
    int k = kb + j;
    float f = (k < HID) ? Whh[g * HID + k] : Wih[g * EMBD + (k - HID)];
    v[j] = tobf(f);
  }
  ((bf16x8*)wsw)[id] = v;
}

// emb -> bf16, biases -> interleaved sum ([4*unit+type], matches C-row interleave)
__global__ void prep_misc(const float* __restrict__ emb,
                          const float* __restrict__ bihf, const float* __restrict__ bhhf,
                          const float* __restrict__ bihb, const float* __restrict__ bhhb,
                          short* __restrict__ embw, float* __restrict__ biasg) {
  int id = blockIdx.x * 256 + threadIdx.x;       // 8192 + 2048 = 10240
  if (id < VOCABSZ * EMBD) {
    embw[id] = tobf(emb[id]);
  } else {
    int r = id - VOCABSZ * EMBD;
    if (r < 2048) {
      int d = r >> 10, n = r & 1023;
      int g = (n & 3) * 256 + (n >> 2);
      biasg[r] = d ? (bihb[g] + bhhb[g]) : (bihf[g] + bhhf[g]);
    }
  }
}

// ---------------- length bucketing ----------------
__global__ void k_hist(const int* __restrict__ lengths, int* __restrict__ hist) {
  int id = blockIdx.x * 256 + threadIdx.x;
  if (id < N_WORDS) atomicAdd(&hist[lengths[id] - 1], 1);
}
__global__ void k_scan(const int* __restrict__ hist, int* __restrict__ basep) {
  if (threadIdx.x == 0 && blockIdx.x == 0) {
    int s = 0;
    for (int i = 0; i < 16; ++i) { basep[i] = s; s += hist[i]; }
  }
}
__global__ void k_scat(const int* __restrict__ lengths, const int* __restrict__ basep,
                       int* __restrict__ cnt, int* __restrict__ sorted) {
  int id = blockIdx.x * 256 + threadIdx.x;
  if (id < N_WORDS) {
    int b = lengths[id] - 1;
    int p = basep[b] + atomicAdd(&cnt[b], 1);
    sorted[p] = id;
  }
}

// ---------------- main fused BiLSTM kernel ----------------
// OPERAND SWAP vs R6: weights are the MFMA A-operand (rows = 4 units x 4 gates,
// unit-major interleave), [h|x] is the B-operand. C tile: row=quad*4+reg, col=lane&15
// => lane's 4 acc regs = i,f,g,o of ONE (unit,word). No cross-lane transpose at all.
//   lane owns: unit u = 64*wv + 4*rt + quad, word w = ct*16 + (lane&15)
__global__ __launch_bounds__(256, 1) void lstm_main(
    const int* __restrict__ char_ids, const int* __restrict__ lengths,
    const short* __restrict__ wsw, const short* __restrict__ embw,
    const float* __restrict__ biasg, const int* __restrict__ sorted,
    float* __restrict__ cws, float* __restrict__ out) {
  __shared__ __align__(16) short A[M_TILE * AROW];   // [word][ h(256) | x(64) | pad(8) ] bf16
  __shared__ __align__(16) int   charl[M_TILE * 16];
  __shared__ __align__(16) float biasl[GATES];
  __shared__ int lenl[M_TILE];
  __shared__ int swl[M_TILE];

  const int tid  = threadIdx.x;
  const int lane = tid & 63;
  const int wv   = tid >> 6;
  const int quad = lane >> 4;
  const int colc = lane & 15;
  const int pb   = blockIdx.x;
  const int dir  = pb & 1;
  const int qb   = pb >> 1;
  const int tile = (qb & 1) ? (255 - (qb >> 1)) : (qb >> 1);

  // this block's c slice: [wv][rt][ct][lane] scalar fp32 (256 B coalesced per wave access)
  float* cb = cws + (size_t)pb * (4 * 16 * 4 * 64);

  if (tid < M_TILE) {
    int sw = sorted[tile * M_TILE + tid];
    swl[tid]  = sw;
    lenl[tid] = lengths[sw];
  }
  ((f32x4*)biasl)[tid] = ((const f32x4*)(biasg + dir * GATES))[tid];
  for (int i = tid; i < M_TILE * AROW / 2; i += 256) ((int*)A)[i] = 0;     // h=0 init
  for (int i = tid; i < 4 * 16 * 4 * 64 / 4; i += 256)
    ((f32x4*)cb)[i] = (f32x4){0.f, 0.f, 0.f, 0.f};                         // c=0 init
  __syncthreads();

  { // char ids for the tile (via sorted ids)
    int w = tid >> 2, ch = tid & 3;
    ((i32x4*)charl)[tid] = ((const i32x4*)(char_ids + swl[w] * 16))[ch];
  }
  int Lmax = lenl[lane];
  for (int o = 32; o; o >>= 1) { int v = __shfl_xor(Lmax, o, 64); Lmax = Lmax > v ? Lmax : v; }
  __syncthreads();  // charl ready

  // stage x for timestep tt into A cols [256,320): wave w covers words 16w..16w+15, 4 lanes/word
  auto gather_x = [&](int tt) {
    int wl = wv * 16 + (lane >> 2);
    int part = lane & 3;
    int lw = lenl[wl];
    int pos = (dir == 0) ? tt : (lw - 1 - tt);
    pos = pos < 0 ? 0 : (pos > 15 ? 15 : pos);
    int cid = charl[wl * 16 + pos];
    const bf16x8* src = (const bf16x8*)(embw + cid * EMBD + part * 16);
    bf16x8 e0 = src[0], e1 = src[1];
    *(bf16x8*)(A + wl * AROW + HID + part * 16)     = e0;
    *(bf16x8*)(A + wl * AROW + HID + part * 16 + 8) = e1;
  };
  gather_x(0);

  // step-invariant lane constants (word dimension, per col-tile ct)
  int lenw[4], hadrb[4], oadr[4];
#pragma unroll
  for (int ct = 0; ct < 4; ++ct) {
    int wl = ct * 16 + colc;
    lenw[ct]  = lenl[wl];
    hadrb[ct] = wl * AROW + 64 * wv + quad;                  // + 4*rt : bf16 h slot in A
    oadr[ct]  = swl[wl] * 512 + dir * 256 + 64 * wv + quad;  // + 4*rt : fp32 out slot
  }
  const short* wp = wsw + ((size_t)dir * 64 + wv * 16) * 10 * 64 * 8 + lane * 8;
  float* cwl = cb + wv * (16 * 4 * 64) + lane;   // + (rt*4+ct)*64

  __syncthreads();  // x / zeros visible

#pragma unroll 1
  for (int t = 0; t < Lmax; ++t) {
    bf16x8 wA[10], wB[10];
#pragma unroll
    for (int kk = 0; kk < 10; ++kk) wA[kk] = *(const bf16x8*)(wp + kk * 512);

    bf16x8 hx[4][10];  // B fragments: lane = B[k = kk*32 + quad*8 + j][n = ct*16 + colc]
#pragma unroll
    for (int ct = 0; ct < 4; ++ct)
#pragma unroll
      for (int kk = 0; kk < 10; ++kk)
        hx[ct][kk] = *(const bf16x8*)(A + (ct * 16 + colc) * AROW + kk * 32 + quad * 8);

    __syncthreads();  // all waves snapshotted A -> safe to overwrite h/x below

    auto wtile = [&](int rt, bf16x8(&wc)[10], bf16x8(&wn)[10], int pre) {
      if (pre >= 0) {  // prefetch next row-tile's weight frags (vmcnt stays > 0)
#pragma unroll
        for (int kk = 0; kk < 10; ++kk) wn[kk] = *(const bf16x8*)(wp + (pre * 10 + kk) * 512);
      }
      float co[4];
#pragma unroll
      for (int ct = 0; ct < 4; ++ct) co[ct] = cwl[(rt * 4 + ct) * 64];  // coalesced, early
      // bias for lane's unit: one f32x4 = (b_i, b_f, b_g, b_o)
      f32x4 bias4 = *(const f32x4*)(biasl + 256 * wv + 16 * rt + 4 * quad);
      f32x4 acc[4];
#pragma unroll
      for (int ct = 0; ct < 4; ++ct) acc[ct] = bias4;
#pragma unroll
      for (int kk = 0; kk < 10; ++kk)
#pragma unroll
        for (int ct = 0; ct < 4; ++ct)  // 4 independent acc chains -> MFMA ILP
          acc[ct] = __builtin_amdgcn_mfma_f32_16x16x32_bf16(wc[kk], hx[ct][kk], acc[ct], 0, 0, 0);

#pragma unroll
      for (int ct = 0; ct < 4; ++ct) {
        // lane-private epilogue: regs = i,f,g,o of (unit 64wv+4rt+quad, word ct*16+colc)
        float ig = fsig(acc[ct][0]);
        float fg = fsig(acc[ct][1]);
        float gg = ftanhf(acc[ct][2]);
        float og = fsig(acc[ct][3]);
        float co_v = co[ct];
        float c2 = fg * co_v + ig * gg;
        float h2 = og * ftanhf(c2);
        bool act = t < lenw[ct];
        cwl[(rt * 4 + ct) * 64] = act ? c2 : co_v;
        if (act) A[hadrb[ct] + 4 * rt] = tobf(h2);              // freeze h when masked
        if (t == lenw[ct] - 1) out[oadr[ct] + 4 * rt] = h2;     // final h in fp32
      }
    };

#pragma unroll 1
    for (int rt2 = 0; rt2 < 16; rt2 += 2) {   // ping-pong weight buffers, static indices
      wtile(rt2,     wA, wB, rt2 + 1);
      wtile(rt2 + 1, wB, wA, (rt2 + 2 < 16) ? (rt2 + 2) : -1);
    }

    gather_x(t + 1);   // x for next step (clamped; dead steps are masked)
    __syncthreads();   // h/x writes visible before next step's reads
  }
}

// ---------------- launch ----------------
extern "C" void kernel_launch(void* const* d_in, const int* in_sizes, int n_in,
                              void* d_out, int out_size, void* d_ws, size_t ws_size,
                              hipStream_t stream) {
  const int*   char_ids = (const int*)d_in[0];
  const int*   lengths  = (const int*)d_in[1];
  const float* emb      = (const float*)d_in[2];
  const float* Wihf     = (const float*)d_in[3];
  const float* Whhf     = (const float*)d_in[4];
  const float* bihf     = (const float*)d_in[5];
  const float* bhhf     = (const float*)d_in[6];
  const float* Wihb     = (const float*)d_in[7];
  const float* Whhb     = (const float*)d_in[8];
  const float* bihb     = (const float*)d_in[9];
  const float* bhhb     = (const float*)d_in[10];

  char* ws = (char*)d_ws;
  short* wsw   = (short*)(ws + OFF_WSW);
  short* embw  = (short*)(ws + OFF_EMB);
  float* biasg = (float*)(ws + OFF_BIAS);
  int*   sortd = (int*)(ws + OFF_SORT);
  int*   hist  = (int*)(ws + OFF_HIST);
  int*   basep = (int*)(ws + OFF_BASE);
  int*   cnt   = (int*)(ws + OFF_CNT);
  float* cws   = (float*)(ws + OFF_C);

  hipMemsetAsync(hist, 0, 192, stream);  // hist + base + cnt
  k_hist<<<64, 256, 0, stream>>>(lengths, hist);
  k_scan<<<1, 64, 0, stream>>>(hist, basep);
  k_scat<<<64, 256, 0, stream>>>(lengths, basep, cnt, sortd);
  prep_w<<<320, 256, 0, stream>>>(Wihf, Whhf, Wihb, Whhb, wsw);
  prep_misc<<<40, 256, 0, stream>>>(emb, bihf, bhhf, bihb, bhhb, embw, biasg);
  lstm_main<<<512, 256, 0, stream>>>(char_ids, lengths, wsw, embw, biasg, sortd,
                                     cws, (float*)d_out);
}